// Round 1
// baseline (839.612 us; speedup 1.0000x reference)
//
#include <hip/hip_runtime.h>
#include <math.h>

// Problem constants (fixed by setup_inputs)
#define B_   512
#define S_   128
#define T_   24
#define D_   256
#define H_   4
#define HD_  64
#define N_   (B_*S_)
#define NEG_INF_ -1e9f

// Workspace layout (float offsets)
#define OFF_K    0            // [24][256]
#define OFF_V    6144         // [24][256]
#define OFF_QT   12288        // [24][256]  (qt + bq folded in)
#define OFF_VU   18432        // [96][256]  j = h*24+t
#define OFF_ST   43008        // [24][4][24]
#define OFF_SU   45312        // [512][4][24]
#define OFF_ATTN 94464        // [N][96]
// total = 6,385,920 floats = 25.5 MB

// P1: k[t][d], v[t][d], qt'[t][d] = ts[t] @ W + bias   (72 blocks x 256)
__global__ void precompute1(const float* __restrict__ ts,
                            const float* __restrict__ Wk, const float* __restrict__ bk,
                            const float* __restrict__ Wv, const float* __restrict__ bv,
                            const float* __restrict__ Wq, const float* __restrict__ bq,
                            float* __restrict__ ws) {
    int blk = blockIdx.x;          // 0..71
    int mat = blk / T_;            // 0=k, 1=v, 2=qt
    int t   = blk % T_;
    int d   = threadIdx.x;
    const float* W; const float* bias; float* dst;
    if (mat == 0)      { W = Wk;           bias = bk; dst = ws + OFF_K;  }
    else if (mat == 1) { W = Wv;           bias = bv; dst = ws + OFF_V;  }
    else               { W = Wq + D_*D_;   bias = bq; dst = ws + OFF_QT; }  // time half of Wq
    float acc = bias[d];
    #pragma unroll 8
    for (int j = 0; j < D_; ++j)
        acc += ts[t*D_ + j] * W[j*D_ + d];
    dst[t*D_ + d] = acc;
}

// P2: vu[j=h*24+t][d] = v[t, h*64:..] @ Wu[h*64:..., d]  (blocks 0..95)
//     st[t'][h][t]    = qt'[t']·k[t] over head slice      (block 96)
__global__ void precompute2(const float* __restrict__ Wu, float* __restrict__ ws) {
    const float* v  = ws + OFF_V;
    const float* k  = ws + OFF_K;
    const float* qt = ws + OFF_QT;
    int blk = blockIdx.x;
    if (blk < 96) {
        int h = blk / T_, t = blk % T_;
        int d = threadIdx.x;
        float acc = 0.f;
        #pragma unroll 8
        for (int l = 0; l < HD_; ++l)
            acc += v[t*D_ + h*HD_ + l] * Wu[(h*HD_ + l)*D_ + d];
        ws[OFF_VU + (h*T_ + t)*D_ + d] = acc;
    } else {
        // 2304 st values, 9 per thread
        for (int i = 0; i < 9; ++i) {
            int idx = threadIdx.x*9 + i;       // 0..2303
            int tp = idx / 96; int rem = idx % 96;
            int h = rem / T_, t = rem % T_;
            float acc = 0.f;
            #pragma unroll 8
            for (int l = 0; l < HD_; ++l)
                acc += qt[tp*D_ + h*HD_ + l] * k[t*D_ + h*HD_ + l];
            ws[OFF_ST + idx] = acc;
        }
    }
}

// P3: qu[b] = upref[user[b]] @ Wq_top (LDS), then su[b][h][t] = qu·k  (512 blocks x 256)
__global__ void user_su(const int* __restrict__ user,
                        const float* __restrict__ upref,
                        const float* __restrict__ Wq,
                        float* __restrict__ ws) {
    __shared__ float qu[D_];
    int b = blockIdx.x;
    int d = threadIdx.x;
    int u = user[b];
    const float* up = upref + (size_t)u * D_;
    float acc = 0.f;
    #pragma unroll 8
    for (int j = 0; j < D_; ++j)
        acc += up[j] * Wq[j*D_ + d];
    qu[d] = acc;
    __syncthreads();
    if (d < 96) {                       // d = h*24 + t
        int h = d / T_, t = d % T_;
        const float* k = ws + OFF_K;
        float s = 0.f;
        #pragma unroll 8
        for (int l = 0; l < HD_; ++l)
            s += qu[h*HD_ + l] * k[t*D_ + h*HD_ + l];
        ws[OFF_SU + b*96 + d] = s;
    }
}

// C1: attn[n][h*24+t] = softmax over t of masked scores   (1024 blocks x 256, thread per (n,h))
__global__ void attn_kernel(const int* __restrict__ hour,
                            const int* __restrict__ hmask,
                            float* __restrict__ ws) {
    int g = blockIdx.x * 256 + threadIdx.x;   // 0..262143
    int n = g >> 2, h = g & 3;
    int b = n >> 7;                           // S = 128
    int hr = hour[n];
    const float* su = ws + OFF_SU + b*96 + h*T_;
    const float* st = ws + OFF_ST + hr*96 + h*T_;
    const int*   m  = hmask + (size_t)n*T_;
    float s[T_];
    float mx = -3.0e38f;
    #pragma unroll
    for (int t = 0; t < T_; ++t) {
        float v = (su[t] + st[t]) * 0.125f;   // scale = 1/sqrt(64)
        if (m[t] == 1) v = NEG_INF_;
        s[t] = v;
        mx = fmaxf(mx, v);
    }
    float sum = 0.f;
    #pragma unroll
    for (int t = 0; t < T_; ++t) {
        float e = __expf(s[t] - mx);
        s[t] = e; sum += e;
    }
    float inv = 1.f / sum;
    float* out = ws + OFF_ATTN + (size_t)n*96 + h*T_;
    #pragma unroll
    for (int t = 0; t < T_; ++t)
        out[t] = s[t] * inv;
}

// C2: out[n][d] = bu[d] + sum_j attn[n][j] * vu[j][d]     (1024 blocks x 256, 64 n per block)
//     vu column held in 96 VGPRs per lane; attn reads are wave-uniform (broadcast/scalar).
__global__ void out_kernel(const float* __restrict__ ws,
                           const float* __restrict__ bu,
                           float* __restrict__ out) {
    int d = threadIdx.x;                       // 0..255
    const float* vu   = ws + OFF_VU;
    const float* attn = ws + OFF_ATTN;
    float vr[96];
    #pragma unroll
    for (int j = 0; j < 96; ++j) vr[j] = vu[j*D_ + d];
    float bias = bu[d];
    int n0 = blockIdx.x * 64;
    for (int nn = 0; nn < 64; nn += 2) {
        int n = n0 + nn;
        const float* a0 = attn + (size_t)n * 96;
        const float* a1 = a0 + 96;
        float acc0 = bias, acc1 = bias;
        #pragma unroll
        for (int j = 0; j < 96; ++j) {
            acc0 += a0[j] * vr[j];
            acc1 += a1[j] * vr[j];
        }
        out[(size_t)n*D_ + d]     = acc0;
        out[(size_t)(n+1)*D_ + d] = acc1;
    }
}

extern "C" void kernel_launch(void* const* d_in, const int* in_sizes, int n_in,
                              void* d_out, int out_size, void* d_ws, size_t ws_size,
                              hipStream_t stream) {
    const float* ts    = (const float*)d_in[0];
    const int*   user  = (const int*)  d_in[1];
    const int*   hour  = (const int*)  d_in[2];
    const int*   hmask = (const int*)  d_in[3];
    const float* upref = (const float*)d_in[4];
    const float* Wq    = (const float*)d_in[5];
    const float* bq    = (const float*)d_in[6];
    const float* Wk    = (const float*)d_in[7];
    const float* bk    = (const float*)d_in[8];
    const float* Wv    = (const float*)d_in[9];
    const float* bv    = (const float*)d_in[10];
    const float* Wu    = (const float*)d_in[11];
    const float* bu    = (const float*)d_in[12];
    float* out = (float*)d_out;
    float* ws  = (float*)d_ws;

    precompute1<<<72, 256, 0, stream>>>(ts, Wk, bk, Wv, bv, Wq, bq, ws);
    precompute2<<<97, 256, 0, stream>>>(Wu, ws);
    user_su<<<B_, 256, 0, stream>>>(user, upref, Wq, ws);
    attn_kernel<<<(N_*H_)/256, 256, 0, stream>>>(hour, hmask, ws);
    out_kernel<<<N_/64, 256, 0, stream>>>(ws, bu, out);
}

// Round 2
// 313.013 us; speedup vs baseline: 2.6824x; 2.6824x over previous
//
#include <hip/hip_runtime.h>
#include <math.h>

// Problem constants (fixed by setup_inputs)
#define B_   512
#define S_   128
#define T_   24
#define D_   256
#define H_   4
#define HD_  64
#define N_   (B_*S_)
#define NEG_INF_ -1e9f

// Workspace layout (float offsets)
#define OFF_K    0            // [24][256]
#define OFF_V    6144         // [24][256]
#define OFF_QT   12288        // [24][256]  (qt + bq folded in)
#define OFF_VU   18432        // [96][256]  j = h*24+t
#define OFF_ST   43008        // [24][4][24]
#define OFF_SU   45312        // [512][4][24]
// total = 94,464 floats = 378 KB

// P1: k[t][d], v[t][d], qt'[t][d] = ts[t] @ W + bias   (72 blocks x 256)
__global__ void precompute1(const float* __restrict__ ts,
                            const float* __restrict__ Wk, const float* __restrict__ bk,
                            const float* __restrict__ Wv, const float* __restrict__ bv,
                            const float* __restrict__ Wq, const float* __restrict__ bq,
                            float* __restrict__ ws) {
    int blk = blockIdx.x;          // 0..71
    int mat = blk / T_;            // 0=k, 1=v, 2=qt
    int t   = blk % T_;
    int d   = threadIdx.x;
    const float* W; const float* bias; float* dst;
    if (mat == 0)      { W = Wk;           bias = bk; dst = ws + OFF_K;  }
    else if (mat == 1) { W = Wv;           bias = bv; dst = ws + OFF_V;  }
    else               { W = Wq + D_*D_;   bias = bq; dst = ws + OFF_QT; }  // time half of Wq
    float acc = bias[d];
    #pragma unroll 8
    for (int j = 0; j < D_; ++j)
        acc += ts[t*D_ + j] * W[j*D_ + d];
    dst[t*D_ + d] = acc;
}

// P2: vu[j=h*24+t][d] = v[t, h*64:..] @ Wu[h*64:..., d]  (blocks 0..95)
//     st[t'][h][t]    = qt'[t']·k[t] over head slice      (block 96)
__global__ void precompute2(const float* __restrict__ Wu, float* __restrict__ ws) {
    const float* v  = ws + OFF_V;
    const float* k  = ws + OFF_K;
    const float* qt = ws + OFF_QT;
    int blk = blockIdx.x;
    if (blk < 96) {
        int h = blk / T_, t = blk % T_;
        int d = threadIdx.x;
        float acc = 0.f;
        #pragma unroll 8
        for (int l = 0; l < HD_; ++l)
            acc += v[t*D_ + h*HD_ + l] * Wu[(h*HD_ + l)*D_ + d];
        ws[OFF_VU + (h*T_ + t)*D_ + d] = acc;
    } else {
        // 2304 st values, 9 per thread
        for (int i = 0; i < 9; ++i) {
            int idx = threadIdx.x*9 + i;       // 0..2303
            int tp = idx / 96; int rem = idx % 96;
            int h = rem / T_, t = rem % T_;
            float acc = 0.f;
            #pragma unroll 8
            for (int l = 0; l < HD_; ++l)
                acc += qt[tp*D_ + h*HD_ + l] * k[t*D_ + h*HD_ + l];
            ws[OFF_ST + idx] = acc;
        }
    }
}

// P3: qu[b] = upref[user[b]] @ Wq_top (LDS), then su[b][h][t] = qu·k  (512 blocks x 256)
__global__ void user_su(const int* __restrict__ user,
                        const float* __restrict__ upref,
                        const float* __restrict__ Wq,
                        float* __restrict__ ws) {
    __shared__ float qu[D_];
    int b = blockIdx.x;
    int d = threadIdx.x;
    int u = user[b];
    const float* up = upref + (size_t)u * D_;
    float acc = 0.f;
    #pragma unroll 8
    for (int j = 0; j < D_; ++j)
        acc += up[j] * Wq[j*D_ + d];
    qu[d] = acc;
    __syncthreads();
    if (d < 96) {                       // d = h*24 + t
        int h = d / T_, t = d % T_;
        const float* k = ws + OFF_K;
        float s = 0.f;
        #pragma unroll 8
        for (int l = 0; l < HD_; ++l)
            s += qu[h*HD_ + l] * k[t*D_ + h*HD_ + l];
        ws[OFF_SU + b*96 + d] = s;
    }
}

// C (fused): per block of 64 rows — softmax into LDS, barrier, GEMV vs vu.
// Phase 1: thread = (r=tid>>2, h=tid&3) computes 24 softmax'd attn values -> LDS.
// Phase 2: thread = output column d; attn read as wave-uniform ds_read_b128 broadcast.
__global__ __launch_bounds__(256) void fused_attn_out(
        const int* __restrict__ hour,
        const int* __restrict__ hmask,
        const float* __restrict__ ws,
        const float* __restrict__ bu,
        float* __restrict__ out) {
    __shared__ float attn_lds[64][100];   // pad 96->100 (row stride 400B, 16B-aligned)
    int tid = threadIdx.x;
    int n0  = blockIdx.x * 64;
    int b   = n0 >> 7;                    // S=128 -> one b per block

    // ---- phase 1: attention weights for 64 rows ----
    {
        int r = tid >> 2, h = tid & 3;
        int n = n0 + r;
        int hr = hour[n];
        const float4* su4 = (const float4*)(ws + OFF_SU + b*96  + h*T_);
        const float4* st4 = (const float4*)(ws + OFF_ST + hr*96 + h*T_);
        const int4*   m4  = (const int4*)(hmask + (size_t)n * T_);
        float s[T_];
        float mx = -3.0e38f;
        #pragma unroll
        for (int i = 0; i < 6; ++i) {
            float4 a = su4[i];
            float4 c = st4[i];
            int4   m = m4[i];
            float v0 = (m.x == 1) ? NEG_INF_ : (a.x + c.x) * 0.125f;
            float v1 = (m.y == 1) ? NEG_INF_ : (a.y + c.y) * 0.125f;
            float v2 = (m.z == 1) ? NEG_INF_ : (a.z + c.z) * 0.125f;
            float v3 = (m.w == 1) ? NEG_INF_ : (a.w + c.w) * 0.125f;
            s[4*i+0] = v0; s[4*i+1] = v1; s[4*i+2] = v2; s[4*i+3] = v3;
            mx = fmaxf(mx, fmaxf(fmaxf(v0, v1), fmaxf(v2, v3)));
        }
        float sum = 0.f;
        #pragma unroll
        for (int t = 0; t < T_; ++t) {
            float e = __expf(s[t] - mx);
            s[t] = e; sum += e;
        }
        float inv = 1.f / sum;
        #pragma unroll
        for (int i = 0; i < 6; ++i) {
            float4 e4 = make_float4(s[4*i+0]*inv, s[4*i+1]*inv,
                                    s[4*i+2]*inv, s[4*i+3]*inv);
            *(float4*)&attn_lds[r][h*T_ + 4*i] = e4;
        }
    }
    __syncthreads();

    // ---- phase 2: out[n][d] = bu[d] + sum_j attn[n][j] * vu[j][d] ----
    {
        int d = tid;
        const float* vu = ws + OFF_VU;
        float vr[96];
        #pragma unroll
        for (int j = 0; j < 96; ++j) vr[j] = vu[j*D_ + d];
        float bias = bu[d];
        float* op = out + (size_t)n0 * D_ + d;
        for (int r = 0; r < 64; ++r) {
            const float4* ap = (const float4*)&attn_lds[r][0];
            float a0 = bias, a1 = 0.f, a2 = 0.f, a3 = 0.f;
            #pragma unroll
            for (int jv = 0; jv < 24; ++jv) {
                float4 a = ap[jv];
                a0 += a.x * vr[4*jv+0];
                a1 += a.y * vr[4*jv+1];
                a2 += a.z * vr[4*jv+2];
                a3 += a.w * vr[4*jv+3];
            }
            op[(size_t)r * D_] = (a0 + a1) + (a2 + a3);
        }
    }
}

extern "C" void kernel_launch(void* const* d_in, const int* in_sizes, int n_in,
                              void* d_out, int out_size, void* d_ws, size_t ws_size,
                              hipStream_t stream) {
    const float* ts    = (const float*)d_in[0];
    const int*   user  = (const int*)  d_in[1];
    const int*   hour  = (const int*)  d_in[2];
    const int*   hmask = (const int*)  d_in[3];
    const float* upref = (const float*)d_in[4];
    const float* Wq    = (const float*)d_in[5];
    const float* bq    = (const float*)d_in[6];
    const float* Wk    = (const float*)d_in[7];
    const float* bk    = (const float*)d_in[8];
    const float* Wv    = (const float*)d_in[9];
    const float* bv    = (const float*)d_in[10];
    const float* Wu    = (const float*)d_in[11];
    const float* bu    = (const float*)d_in[12];
    float* out = (float*)d_out;
    float* ws  = (float*)d_ws;

    precompute1<<<72, 256, 0, stream>>>(ts, Wk, bk, Wv, bv, Wq, bq, ws);
    precompute2<<<97, 256, 0, stream>>>(Wu, ws);
    user_su<<<B_, 256, 0, stream>>>(user, upref, Wq, ws);
    fused_attn_out<<<N_/64, 256, 0, stream>>>(hour, hmask, ws, bu, out);
}

// Round 3
// 245.432 us; speedup vs baseline: 3.4210x; 1.2754x over previous
//
#include <hip/hip_runtime.h>
#include <math.h>

// Problem constants (fixed by setup_inputs)
#define B_   512
#define S_   128
#define T_   24
#define D_   256
#define H_   4
#define HD_  64
#define N_   (B_*S_)
#define NEG_INF_ -1e9f

typedef unsigned int  u32;
typedef unsigned short u16;
typedef _Float16 f16;
typedef _Float16 f16x8 __attribute__((ext_vector_type(8)));
typedef float    f32x4 __attribute__((ext_vector_type(4)));
typedef u32      u32x4 __attribute__((ext_vector_type(4)));

// Workspace layout (float offsets)
#define OFF_K    0            // [24][256] f32
#define OFF_V    6144         // [24][256] f32
#define OFF_QT   12288        // [24][256] f32 (qt + bq folded in)
#define OFF_ST   18432        // [24][4][24] f32
#define OFF_SU   20736        // [512][4][24] f32
#define OFF_VUT  69888        // [256 cols][96 k] f16 (stored as u16; 12288 floats)
// total = 82,176 floats = 329 KB

__device__ inline u32 pack2f16(float a, float b) {
    u16 ha = __builtin_bit_cast(u16, (f16)a);
    u16 hb = __builtin_bit_cast(u16, (f16)b);
    return (u32)ha | ((u32)hb << 16);
}

// P1: k[t][d], v[t][d], qt'[t][d] = ts[t] @ W + bias   (72 blocks x 256)
__global__ void precompute1(const float* __restrict__ ts,
                            const float* __restrict__ Wk, const float* __restrict__ bk,
                            const float* __restrict__ Wv, const float* __restrict__ bv,
                            const float* __restrict__ Wq, const float* __restrict__ bq,
                            float* __restrict__ ws) {
    int blk = blockIdx.x;          // 0..71
    int mat = blk / T_;            // 0=k, 1=v, 2=qt
    int t   = blk % T_;
    int d   = threadIdx.x;
    const float* W; const float* bias; float* dst;
    if (mat == 0)      { W = Wk;           bias = bk; dst = ws + OFF_K;  }
    else if (mat == 1) { W = Wv;           bias = bv; dst = ws + OFF_V;  }
    else               { W = Wq + D_*D_;   bias = bq; dst = ws + OFF_QT; }  // time half of Wq
    float acc = bias[d];
    #pragma unroll 8
    for (int j = 0; j < D_; ++j)
        acc += ts[t*D_ + j] * W[j*D_ + d];
    dst[t*D_ + d] = acc;
}

// P2: vuT[d][h*24+t] = (f16)(v[t, h*64:..] @ Wu[h*64:..., d])  (blocks 0..95)
//     st[t'][h][t]   = qt'[t']·k[t] over head slice             (block 96)
__global__ void precompute2(const float* __restrict__ Wu, float* __restrict__ ws) {
    const float* v  = ws + OFF_V;
    const float* k  = ws + OFF_K;
    const float* qt = ws + OFF_QT;
    int blk = blockIdx.x;
    if (blk < 96) {
        int h = blk / T_, t = blk % T_;
        int d = threadIdx.x;
        float acc = 0.f;
        #pragma unroll 8
        for (int l = 0; l < HD_; ++l)
            acc += v[t*D_ + h*HD_ + l] * Wu[(h*HD_ + l)*D_ + d];
        u16* vuT = (u16*)(ws + OFF_VUT);
        vuT[d*96 + h*T_ + t] = __builtin_bit_cast(u16, (f16)acc);
    } else {
        for (int i = 0; i < 9; ++i) {
            int idx = threadIdx.x*9 + i;       // 0..2303
            int tp = idx / 96; int rem = idx % 96;
            int h = rem / T_, t = rem % T_;
            float acc = 0.f;
            #pragma unroll 8
            for (int l = 0; l < HD_; ++l)
                acc += qt[tp*D_ + h*HD_ + l] * k[t*D_ + h*HD_ + l];
            ws[OFF_ST + idx] = acc;
        }
    }
}

// P3: qu[b] = upref[user[b]] @ Wq_top (LDS), then su[b][h][t] = qu·k  (512 blocks x 256)
__global__ void user_su(const int* __restrict__ user,
                        const float* __restrict__ upref,
                        const float* __restrict__ Wq,
                        float* __restrict__ ws) {
    __shared__ float qu[D_];
    int b = blockIdx.x;
    int d = threadIdx.x;
    int u = user[b];
    const float* up = upref + (size_t)u * D_;
    float acc = 0.f;
    #pragma unroll 8
    for (int j = 0; j < D_; ++j)
        acc += up[j] * Wq[j*D_ + d];
    qu[d] = acc;
    __syncthreads();
    if (d < 96) {                       // d = h*24 + t
        int h = d / T_, t = d % T_;
        const float* k = ws + OFF_K;
        float s = 0.f;
        #pragma unroll 8
        for (int l = 0; l < HD_; ++l)
            s += qu[h*HD_ + l] * k[t*D_ + h*HD_ + l];
        ws[OFF_SU + b*96 + d] = s;
    }
}

// Fused: softmax -> f16 A-fragments in LDS -> MFMA GEMM (64x96 @ 96x256) -> out.
// A-fragment layout for mfma_f32_16x16x32_f16: lane = kgroup*16 + row, lane holds
// 8 contiguous k (k = kgroup*8 + j) per 16x32 k-tile. atile dword index:
// ((mtile*3 + ktile)*64 + lane)*4 + (k&7)/2.
__global__ __launch_bounds__(256) void fused_attn_out(
        const int* __restrict__ hour,
        const int* __restrict__ hmask,
        const float* __restrict__ ws,
        const float* __restrict__ bu,
        float* __restrict__ out) {
    __shared__ __align__(16) u32 atile[3072];   // 4 mtiles x 3 ktiles x 64 lanes x 16B = 12 KB
    int tid = threadIdx.x;
    int n0  = blockIdx.x * 64;
    int b   = n0 >> 7;                    // S=128 -> one b per block

    // ---- phase 1: softmax for 64 rows, thread = (r = tid>>2, h = tid&3) ----
    {
        int r = tid >> 2, h = tid & 3;
        int n = n0 + r;
        int hr = hour[n];
        const float4* su4 = (const float4*)(ws + OFF_SU + b*96  + h*T_);
        const float4* st4 = (const float4*)(ws + OFF_ST + hr*96 + h*T_);
        const int4*   m4  = (const int4*)(hmask + (size_t)n * T_);
        float s[T_];
        float mx = -3.0e38f;
        #pragma unroll
        for (int i = 0; i < 6; ++i) {
            float4 a = su4[i];
            float4 c = st4[i];
            int4   m = m4[i];
            float v0 = (m.x == 1) ? NEG_INF_ : (a.x + c.x) * 0.125f;
            float v1 = (m.y == 1) ? NEG_INF_ : (a.y + c.y) * 0.125f;
            float v2 = (m.z == 1) ? NEG_INF_ : (a.z + c.z) * 0.125f;
            float v3 = (m.w == 1) ? NEG_INF_ : (a.w + c.w) * 0.125f;
            s[4*i+0] = v0; s[4*i+1] = v1; s[4*i+2] = v2; s[4*i+3] = v3;
            mx = fmaxf(mx, fmaxf(fmaxf(v0, v1), fmaxf(v2, v3)));
        }
        float sum = 0.f;
        #pragma unroll
        for (int t = 0; t < T_; ++t) {
            float e = __expf(s[t] - mx);
            s[t] = e; sum += e;
        }
        float inv = 1.f / sum;
        int mtile = r >> 4, rlane = r & 15;
        #pragma unroll
        for (int i = 0; i < 12; ++i) {
            int t = 2*i;
            int k = 24*h + t;              // 24h % 8 == 0, so pairs never cross dwords
            int ktile = k >> 5;
            int kg    = (k >> 3) & 3;
            int j2    = (k & 7) >> 1;
            atile[((mtile*3 + ktile)*64 + kg*16 + rlane)*4 + j2] =
                pack2f16(s[t]*inv, s[t+1]*inv);
        }
    }
    __syncthreads();

    // ---- phase 2: MFMA GEMM. wave w owns cols [64w, 64w+64) ----
    {
        int w  = tid >> 6;
        int l  = tid & 63;
        int lhi = l >> 4, llo = l & 15;
        const u16* vuT = (const u16*)(ws + OFF_VUT);

        // B fragments: vuT[col][kt*32 + lhi*8 .. +7], one dwordx4 each
        f16x8 bf[4][3];
        #pragma unroll
        for (int nt = 0; nt < 4; ++nt) {
            int col = w*64 + nt*16 + llo;
            #pragma unroll
            for (int kt = 0; kt < 3; ++kt) {
                u32x4 bv = *(const u32x4*)(vuT + col*96 + kt*32 + lhi*8);
                bf[nt][kt] = __builtin_bit_cast(f16x8, bv);
            }
        }

        f32x4 acc[4][4];
        #pragma unroll
        for (int mt = 0; mt < 4; ++mt)
            #pragma unroll
            for (int nt = 0; nt < 4; ++nt)
                acc[mt][nt] = (f32x4){0.f, 0.f, 0.f, 0.f};

        #pragma unroll
        for (int mt = 0; mt < 4; ++mt) {
            f16x8 af[3];
            #pragma unroll
            for (int kt = 0; kt < 3; ++kt) {
                u32x4 av = *(const u32x4*)&atile[((mt*3 + kt)*64 + l)*4];
                af[kt] = __builtin_bit_cast(f16x8, av);
            }
            #pragma unroll
            for (int nt = 0; nt < 4; ++nt) {
                f32x4 c = acc[mt][nt];
                c = __builtin_amdgcn_mfma_f32_16x16x32_f16(af[0], bf[nt][0], c, 0, 0, 0);
                c = __builtin_amdgcn_mfma_f32_16x16x32_f16(af[1], bf[nt][1], c, 0, 0, 0);
                c = __builtin_amdgcn_mfma_f32_16x16x32_f16(af[2], bf[nt][2], c, 0, 0, 0);
                acc[mt][nt] = c;
            }
        }

        // epilogue: D row = mt*16 + lhi*4 + q, col = w*64 + nt*16 + llo
        float bias[4];
        #pragma unroll
        for (int nt = 0; nt < 4; ++nt) bias[nt] = bu[w*64 + nt*16 + llo];
        float* op = out + (size_t)n0 * D_ + w*64 + llo;
        #pragma unroll
        for (int mt = 0; mt < 4; ++mt)
            #pragma unroll
            for (int nt = 0; nt < 4; ++nt)
                #pragma unroll
                for (int q = 0; q < 4; ++q)
                    op[(size_t)(mt*16 + lhi*4 + q) * D_ + nt*16] = acc[mt][nt][q] + bias[nt];
    }
}

extern "C" void kernel_launch(void* const* d_in, const int* in_sizes, int n_in,
                              void* d_out, int out_size, void* d_ws, size_t ws_size,
                              hipStream_t stream) {
    const float* ts    = (const float*)d_in[0];
    const int*   user  = (const int*)  d_in[1];
    const int*   hour  = (const int*)  d_in[2];
    const int*   hmask = (const int*)  d_in[3];
    const float* upref = (const float*)d_in[4];
    const float* Wq    = (const float*)d_in[5];
    const float* bq    = (const float*)d_in[6];
    const float* Wk    = (const float*)d_in[7];
    const float* bk    = (const float*)d_in[8];
    const float* Wv    = (const float*)d_in[9];
    const float* bv    = (const float*)d_in[10];
    const float* Wu    = (const float*)d_in[11];
    const float* bu    = (const float*)d_in[12];
    float* out = (float*)d_out;
    float* ws  = (float*)d_ws;

    precompute1<<<72, 256, 0, stream>>>(ts, Wk, bk, Wv, bv, Wq, bq, ws);
    precompute2<<<97, 256, 0, stream>>>(Wu, ws);
    user_su<<<B_, 256, 0, stream>>>(user, upref, Wq, ws);
    fused_attn_out<<<N_/64, 256, 0, stream>>>(hour, hmask, ws, bu, out);
}

// Round 4
// 224.186 us; speedup vs baseline: 3.7452x; 1.0948x over previous
//
#include <hip/hip_runtime.h>
#include <math.h>

// Problem constants (fixed by setup_inputs)
#define B_   512
#define S_   128
#define T_   24
#define D_   256
#define H_   4
#define HD_  64
#define N_   (B_*S_)
#define NEG_INF_ -1e9f

typedef unsigned int  u32;
typedef unsigned short u16;
typedef _Float16 f16;
typedef _Float16 f16x8 __attribute__((ext_vector_type(8)));
typedef float    f32x4 __attribute__((ext_vector_type(4)));
typedef u32      u32x4 __attribute__((ext_vector_type(4)));

// Workspace layout (float offsets)
#define OFF_K    0            // [24][256] f32
#define OFF_V    6144         // [24][256] f32
#define OFF_QT   12288        // [24][256] f32 (qt + bq folded in)
#define OFF_QU   18432        // [512][256] f32
#define OFF_ST   149504       // [24][4][24] f32
#define OFF_SU   151808       // [512][4][24] f32
#define OFF_VUT  200960       // [256 cols][96 k] f16 (stored as u16; 12288 floats)
// total = 213,248 floats = 853 KB

__device__ inline u32 pack2f16(float a, float b) {
    u16 ha = __builtin_bit_cast(u16, (f16)a);
    u16 hb = __builtin_bit_cast(u16, (f16)b);
    return (u32)ha | ((u32)hb << 16);
}

// S1: blocks 0..71  : k[t][d], v[t][d], qt'[t][d] = ts[t] @ W + bias
//     blocks 72..583: qu[b][d] = upref[user[b]] @ Wq_top   (no bias; bq folded into qt)
__global__ __launch_bounds__(256) void stage1(
        const float* __restrict__ ts,
        const int*   __restrict__ user,
        const float* __restrict__ upref,
        const float* __restrict__ Wk, const float* __restrict__ bk,
        const float* __restrict__ Wv, const float* __restrict__ bv,
        const float* __restrict__ Wq, const float* __restrict__ bq,
        float* __restrict__ ws) {
    int blk = blockIdx.x;
    int d   = threadIdx.x;
    const float* src; const float* W; float acc; float* dst;
    if (blk < 72) {
        int mat = blk / T_;            // 0=k, 1=v, 2=qt
        int t   = blk % T_;
        const float* bias;
        if (mat == 0)      { W = Wk;         bias = bk; dst = ws + OFF_K  + t*D_; }
        else if (mat == 1) { W = Wv;         bias = bv; dst = ws + OFF_V  + t*D_; }
        else               { W = Wq + D_*D_; bias = bq; dst = ws + OFF_QT + t*D_; }
        src = ts + t*D_;
        acc = bias[d];
    } else {
        int b = blk - 72;
        int u = user[b];
        src = upref + (size_t)u * D_;
        W   = Wq;                       // top half
        dst = ws + OFF_QU + b*D_;
        acc = 0.f;
    }
    #pragma unroll 16
    for (int j = 0; j < D_; ++j)
        acc += src[j] * W[j*D_ + d];
    dst[d] = acc;
}

// S2: blocks 0..95 : vuT[d][h*24+t] = (f16)(v[t, h*64:..] @ Wu[h*64:..., d])
//     block 96     : st[t'][h][t]   = qt'[t']·k[t] over head slice
//     blocks 97..608: su[b][h*24+t] = qu[b]·k[t] over head slice
__global__ __launch_bounds__(256) void stage2(
        const float* __restrict__ Wu, float* __restrict__ ws) {
    const float* v  = ws + OFF_V;
    const float* k  = ws + OFF_K;
    const float* qt = ws + OFF_QT;
    int blk = blockIdx.x;
    if (blk < 96) {
        int h = blk / T_, t = blk % T_;
        int d = threadIdx.x;
        float acc = 0.f;
        #pragma unroll 16
        for (int l = 0; l < HD_; ++l)
            acc += v[t*D_ + h*HD_ + l] * Wu[(h*HD_ + l)*D_ + d];
        u16* vuT = (u16*)(ws + OFF_VUT);
        vuT[d*96 + h*T_ + t] = __builtin_bit_cast(u16, (f16)acc);
    } else if (blk == 96) {
        for (int i = 0; i < 9; ++i) {
            int idx = threadIdx.x*9 + i;       // 0..2303
            int tp = idx / 96; int rem = idx % 96;
            int h = rem / T_, t = rem % T_;
            float acc = 0.f;
            #pragma unroll 16
            for (int l = 0; l < HD_; ++l)
                acc += qt[tp*D_ + h*HD_ + l] * k[t*D_ + h*HD_ + l];
            ws[OFF_ST + idx] = acc;
        }
    } else {
        int b = blk - 97;
        int d = threadIdx.x;
        if (d < 96) {
            int h = d / T_, t = d % T_;
            const float* qu = ws + OFF_QU + b*D_;
            float s = 0.f;
            #pragma unroll 16
            for (int l = 0; l < HD_; ++l)
                s += qu[h*HD_ + l] * k[t*D_ + h*HD_ + l];
            ws[OFF_SU + b*96 + d] = s;
        }
    }
}

// Fused: softmax -> f16 A-fragments in LDS -> MFMA GEMM (64x96 @ 96x256) -> out.
// A-fragment layout for mfma_f32_16x16x32_f16: lane = kgroup*16 + row, lane holds
// 8 contiguous k (k = kgroup*8 + j) per 16x32 k-tile. atile dword index:
// ((mtile*3 + ktile)*64 + lane)*4 + (k&7)/2.
__global__ __launch_bounds__(256) void fused_attn_out(
        const int* __restrict__ hour,
        const int* __restrict__ hmask,
        const float* __restrict__ ws,
        const float* __restrict__ bu,
        float* __restrict__ out) {
    __shared__ __align__(16) u32 atile[3072];   // 4 mtiles x 3 ktiles x 64 lanes x 16B = 12 KB
    int tid = threadIdx.x;
    int n0  = blockIdx.x * 64;
    int b   = n0 >> 7;                    // S=128 -> one b per block

    // ---- phase 1: softmax for 64 rows, thread = (r = tid>>2, h = tid&3) ----
    {
        int r = tid >> 2, h = tid & 3;
        int n = n0 + r;
        int hr = hour[n];
        const float4* su4 = (const float4*)(ws + OFF_SU + b*96  + h*T_);
        const float4* st4 = (const float4*)(ws + OFF_ST + hr*96 + h*T_);
        const int4*   m4  = (const int4*)(hmask + (size_t)n * T_);
        float s[T_];
        float mx = -3.0e38f;
        #pragma unroll
        for (int i = 0; i < 6; ++i) {
            float4 a = su4[i];
            float4 c = st4[i];
            int4   m = m4[i];
            float v0 = (m.x == 1) ? NEG_INF_ : (a.x + c.x) * 0.125f;
            float v1 = (m.y == 1) ? NEG_INF_ : (a.y + c.y) * 0.125f;
            float v2 = (m.z == 1) ? NEG_INF_ : (a.z + c.z) * 0.125f;
            float v3 = (m.w == 1) ? NEG_INF_ : (a.w + c.w) * 0.125f;
            s[4*i+0] = v0; s[4*i+1] = v1; s[4*i+2] = v2; s[4*i+3] = v3;
            mx = fmaxf(mx, fmaxf(fmaxf(v0, v1), fmaxf(v2, v3)));
        }
        float sum = 0.f;
        #pragma unroll
        for (int t = 0; t < T_; ++t) {
            float e = __expf(s[t] - mx);
            s[t] = e; sum += e;
        }
        float inv = 1.f / sum;
        int mtile = r >> 4, rlane = r & 15;
        #pragma unroll
        for (int i = 0; i < 12; ++i) {
            int t = 2*i;
            int k = 24*h + t;              // 24h % 8 == 0, so pairs never cross dwords
            int ktile = k >> 5;
            int kg    = (k >> 3) & 3;
            int j2    = (k & 7) >> 1;
            atile[((mtile*3 + ktile)*64 + kg*16 + rlane)*4 + j2] =
                pack2f16(s[t]*inv, s[t+1]*inv);
        }
    }
    __syncthreads();

    // ---- phase 2: MFMA GEMM. wave w owns cols [64w, 64w+64) ----
    {
        int w  = tid >> 6;
        int l  = tid & 63;
        int lhi = l >> 4, llo = l & 15;
        const u16* vuT = (const u16*)(ws + OFF_VUT);

        // B fragments: vuT[col][kt*32 + lhi*8 .. +7], one dwordx4 each
        f16x8 bf[4][3];
        #pragma unroll
        for (int nt = 0; nt < 4; ++nt) {
            int col = w*64 + nt*16 + llo;
            #pragma unroll
            for (int kt = 0; kt < 3; ++kt) {
                u32x4 bv = *(const u32x4*)(vuT + col*96 + kt*32 + lhi*8);
                bf[nt][kt] = __builtin_bit_cast(f16x8, bv);
            }
        }

        f32x4 acc[4][4];
        #pragma unroll
        for (int mt = 0; mt < 4; ++mt)
            #pragma unroll
            for (int nt = 0; nt < 4; ++nt)
                acc[mt][nt] = (f32x4){0.f, 0.f, 0.f, 0.f};

        #pragma unroll
        for (int mt = 0; mt < 4; ++mt) {
            f16x8 af[3];
            #pragma unroll
            for (int kt = 0; kt < 3; ++kt) {
                u32x4 av = *(const u32x4*)&atile[((mt*3 + kt)*64 + l)*4];
                af[kt] = __builtin_bit_cast(f16x8, av);
            }
            #pragma unroll
            for (int nt = 0; nt < 4; ++nt) {
                f32x4 c = acc[mt][nt];
                c = __builtin_amdgcn_mfma_f32_16x16x32_f16(af[0], bf[nt][0], c, 0, 0, 0);
                c = __builtin_amdgcn_mfma_f32_16x16x32_f16(af[1], bf[nt][1], c, 0, 0, 0);
                c = __builtin_amdgcn_mfma_f32_16x16x32_f16(af[2], bf[nt][2], c, 0, 0, 0);
                acc[mt][nt] = c;
            }
        }

        // epilogue: D row = mt*16 + lhi*4 + q, col = w*64 + nt*16 + llo
        float bias[4];
        #pragma unroll
        for (int nt = 0; nt < 4; ++nt) bias[nt] = bu[w*64 + nt*16 + llo];
        float* op = out + (size_t)n0 * D_ + w*64 + llo;
        #pragma unroll
        for (int mt = 0; mt < 4; ++mt)
            #pragma unroll
            for (int nt = 0; nt < 4; ++nt)
                #pragma unroll
                for (int q = 0; q < 4; ++q)
                    __builtin_nontemporal_store(acc[mt][nt][q] + bias[nt],
                        &op[(size_t)(mt*16 + lhi*4 + q) * D_ + nt*16]);
    }
}

extern "C" void kernel_launch(void* const* d_in, const int* in_sizes, int n_in,
                              void* d_out, int out_size, void* d_ws, size_t ws_size,
                              hipStream_t stream) {
    const float* ts    = (const float*)d_in[0];
    const int*   user  = (const int*)  d_in[1];
    const int*   hour  = (const int*)  d_in[2];
    const int*   hmask = (const int*)  d_in[3];
    const float* upref = (const float*)d_in[4];
    const float* Wq    = (const float*)d_in[5];
    const float* bq    = (const float*)d_in[6];
    const float* Wk    = (const float*)d_in[7];
    const float* bk    = (const float*)d_in[8];
    const float* Wv    = (const float*)d_in[9];
    const float* bv    = (const float*)d_in[10];
    const float* Wu    = (const float*)d_in[11];
    const float* bu    = (const float*)d_in[12];
    float* out = (float*)d_out;
    float* ws  = (float*)d_ws;

    stage1<<<584, 256, 0, stream>>>(ts, user, upref, Wk, bk, Wv, bv, Wq, bq, ws);
    stage2<<<609, 256, 0, stream>>>(Wu, ws);
    fused_attn_out<<<N_/64, 256, 0, stream>>>(hour, hmask, ws, bu, out);
}